// Round 9
// baseline (172.486 us; speedup 1.0000x reference)
//
#include <hip/hip_runtime.h>
#include <hip/hip_bf16.h>
#include <math.h>

#define BB 16
#define NN_ 4096
#define DD 512
#define LL 64
#define SCALE 0.044194173824159216f
#define RMS_EPS 1e-6f
#define MASKVAL -3.0e38f
#define PSZ (BB * LL * DD)   // 524288
#define ZCH 32               // N-chunks (128 tokens each, 2 tiles of 64)

using bf16x8 = __attribute__((ext_vector_type(8))) short;
using f32x4  = __attribute__((ext_vector_type(4))) float;

__device__ __forceinline__ unsigned short f2bf(float x) {
    return __bfloat16_as_ushort(__float2bfloat16(x));
}

// ---------------- K1: qproj = query @ Wq + bq ----------------
__global__ __launch_bounds__(256) void k_qproj(const float* __restrict__ query, const float* __restrict__ Wq,
                                               const float* __restrict__ bq, float* __restrict__ qproj) {
    const int b = blockIdx.y;
    const int dl = threadIdx.x & 63;
    const int d = (blockIdx.x << 6) + dl;
    const int wv = threadIdx.x >> 6;
    __shared__ float q[DD];
    __shared__ float red[4][64];
    for (int e = threadIdx.x; e < DD; e += 256) q[e] = query[b * DD + e];
    __syncthreads();
    float acc = 0.f;
    #pragma unroll 8
    for (int i = 0; i < 128; ++i) {
        const int e = (wv << 7) + i;
        acc += q[e] * Wq[(size_t)e * DD + d];
    }
    red[wv][dl] = acc;
    __syncthreads();
    if (threadIdx.x < 64) {
        const int dd = (blockIdx.x << 6) + threadIdx.x;
        qproj[(size_t)b * DD + dd] = red[0][threadIdx.x] + red[1][threadIdx.x] +
                                     red[2][threadIdx.x] + red[3][threadIdx.x] + bq[dd];
    }
}

// ---------------- K2: Lk/Qk = rows @ Wk^T, sbL/sbQ = rows . bk ----------------
__global__ __launch_bounds__(256) void k_lkqk(const float* __restrict__ latents, const float* __restrict__ qproj,
                                              const float* __restrict__ Wk, const float* __restrict__ bk,
                                              float* __restrict__ Lk, float* __restrict__ Qk,
                                              float* __restrict__ sbL, float* __restrict__ sbQ) {
    const int r = blockIdx.y;
    const int e0 = blockIdx.x << 6;
    const int tid = threadIdx.x;
    __shared__ float row[DD];
    const float* src = (r < LL) ? (latents + (size_t)r * DD) : (qproj + (size_t)(r - LL) * DD);
    for (int dd = tid; dd < DD; dd += 256) row[dd] = src[dd];
    __syncthreads();
    const int e = e0 + (tid >> 2);
    const int part = tid & 3;
    const float4* w4 = (const float4*)(Wk + (size_t)e * DD);
    const float4* r4 = (const float4*)row;
    float acc = 0.f;
    #pragma unroll 8
    for (int j = 0; j < 32; ++j) {
        const int d4 = part + (j << 2);
        const float4 w = w4[d4], rr = r4[d4];
        acc += w.x * rr.x + w.y * rr.y + w.z * rr.z + w.w * rr.w;
    }
    acc += __shfl_xor(acc, 1);
    acc += __shfl_xor(acc, 2);
    if (part == 0) {
        if (r < LL) Lk[(size_t)r * DD + e] = acc;
        else        Qk[(size_t)(r - LL) * DD + e] = acc;
    }
    if (blockIdx.x == 0 && tid < 64) {
        float p = 0.f;
        #pragma unroll
        for (int dd = tid; dd < DD; dd += 64) p += bk[dd] * row[dd];
        #pragma unroll
        for (int off = 32; off > 0; off >>= 1) p += __shfl_xor(p, off);
        if (tid == 0) { if (r < LL) sbL[r] = p; else sbQ[r - LL] = p; }
    }
}

// ---------------- K2b: LQbf[b][l][d] = bf16(Lk[l][d] + Qk[b][d]) ----------------
__global__ __launch_bounds__(256) void k_lqbf(const float* __restrict__ Lk, const float* __restrict__ Qk,
                                              unsigned short* __restrict__ LQbf) {
    const int l = blockIdx.x, b = blockIdx.y;
    const int d = threadIdx.x << 1;
    const float2 lv = *(const float2*)&Lk[(size_t)l * DD + d];
    const float2 qv = *(const float2*)&Qk[(size_t)b * DD + d];
    const unsigned o = (unsigned)f2bf(lv.x + qv.x) | ((unsigned)f2bf(lv.y + qv.y) << 16);
    *(unsigned*)&LQbf[(size_t)((b << 6) + l) * DD + d] = o;
}

// ---------------- K3: fused flash (v5: 4-wave blocks, no reg cap, no spill) ----------------
// grid (64, 16): x = (eh<<5)|z; blocks x and x+32 share the token tile (same XCD, 32%8==0).
// 256 threads (4 waves). Each block: 128 tokens (2 tiles of 64) x 64 latents x 256-e half.
__global__ __launch_bounds__(256) void k_flash(const float* __restrict__ tokens,
                                               const unsigned short* __restrict__ LQbf,
                                               const float* __restrict__ sbL, const float* __restrict__ sbQ,
                                               const int* __restrict__ pmask,
                                               _Float16* __restrict__ part,
                                               float* __restrict__ mz, float* __restrict__ sz) {
    const int z = blockIdx.x & 31;
    const int eh = blockIdx.x >> 5;
    const int b = blockIdx.y;
    const int tid = threadIdx.x;
    const int lane = tid & 63, w = tid >> 6;
    const int r16 = lane & 15, kl = lane >> 4;

    __shared__ int sB[64][36];            // QK^T token slice [n][d-word], padded rows (144B)
    __shared__ unsigned short sP[64][72]; // P bf16 [l][n], padded rows (144B)
    __shared__ int sT[4][64][20];         // per-wave PV tile [e(64)][n-word], padded rows (80B)
    __shared__ float s_mn[64], s_sum[64], s_rr[64];
    __shared__ float s_pmax[2][64], s_psum[2][64];

    const int wl = w >> 1, wn = w & 1;
    const int lq = wl << 5;             // QK^T wave l-block (32)
    const int nq = wn << 5;             // QK^T wave n-block (32)

    f32x4 acc[4][4];                    // PV: 64 l x 64 e per wave
    #pragma unroll
    for (int m = 0; m < 4; ++m)
        #pragma unroll
        for (int ef = 0; ef < 4; ++ef)
            acc[m][ef] = (f32x4){0.f, 0.f, 0.f, 0.f};

    if (tid < 64) { s_mn[tid] = MASKVAL; s_sum[tid] = 0.f; }
    __syncthreads();

    const float sq = sbQ[b];
    const unsigned short* lqrow0 = &LQbf[(size_t)((b << 6) + lq + r16) * DD];
    const unsigned short* lqrow1 = lqrow0 + (size_t)16 * DD;

    // phase-1 staging geometry: 4 float4 per thread per slice
    const int st_row = tid >> 4;          // token row 0..15 (+16 per s)
    const int st_c4 = (tid & 15) << 2;    // d offset
    // PV slice geometry
    const int e0w = (eh << 8) + (w << 6); // wave's 64-e slice base

    for (int t = 0; t < 2; ++t) {
        const int n0 = (z << 7) + (t << 6);
        f32x4 accS[2][2];
        #pragma unroll
        for (int m = 0; m < 2; ++m)
            #pragma unroll
            for (int nf = 0; nf < 2; ++nf)
                accS[m][nf] = (f32x4){0.f, 0.f, 0.f, 0.f};

        // ---- phase 1: QK^T over 8 d-slices ----
        float4 pf[4];
        #pragma unroll
        for (int s = 0; s < 4; ++s)
            pf[s] = *(const float4*)&tokens[(size_t)((b << 12) + n0 + st_row + (s << 4)) * DD + st_c4];
        #pragma unroll
        for (int s8 = 0; s8 < 8; ++s8) {
            #pragma unroll
            for (int s = 0; s < 4; ++s) {
                int2 wa;
                wa.x = (int)((unsigned)f2bf(pf[s].x) | ((unsigned)f2bf(pf[s].y) << 16));
                wa.y = (int)((unsigned)f2bf(pf[s].z) | ((unsigned)f2bf(pf[s].w) << 16));
                *(int2*)&sB[st_row + (s << 4)][st_c4 >> 1] = wa;
            }
            __syncthreads();
            if (s8 < 7) {
                #pragma unroll
                for (int s = 0; s < 4; ++s)
                    pf[s] = *(const float4*)&tokens[(size_t)((b << 12) + n0 + st_row + (s << 4)) * DD + ((s8 + 1) << 6) + st_c4];
            }
            #pragma unroll
            for (int kk2 = 0; kk2 < 2; ++kk2) {
                const int koff = (s8 << 6) + (kk2 << 5) + (kl << 3);
                const bf16x8 af0 = *(const bf16x8*)&lqrow0[koff];
                const bf16x8 af1 = *(const bf16x8*)&lqrow1[koff];
                #pragma unroll
                for (int nf = 0; nf < 2; ++nf) {
                    const bf16x8 bfr = *(const bf16x8*)&sB[nq + (nf << 4) + r16][(kk2 << 4) + (kl << 2)];
                    accS[0][nf] = __builtin_amdgcn_mfma_f32_16x16x32_bf16(af0, bfr, accS[0][nf], 0, 0, 0);
                    accS[1][nf] = __builtin_amdgcn_mfma_f32_16x16x32_bf16(af1, bfr, accS[1][nf], 0, 0, 0);
                }
            }
            __syncthreads();
        }

        // ---- epilogue: bias+scale+mask, in-register row stats ----
        float sv[2][2][4];
        #pragma unroll
        for (int nf = 0; nf < 2; ++nf) {
            const int ncol = nq + (nf << 4) + r16;
            const int pm = pmask[(size_t)b * NN_ + n0 + ncol];
            #pragma unroll
            for (int m = 0; m < 2; ++m) {
                #pragma unroll
                for (int q = 0; q < 4; ++q) {
                    const float sval = (accS[m][nf][q] + sbL[lq + (m << 4) + (kl << 2) + q] + sq) * SCALE;
                    sv[m][nf][q] = pm ? MASKVAL : sval;
                }
            }
        }
        float tm[2][4];
        #pragma unroll
        for (int m = 0; m < 2; ++m)
            #pragma unroll
            for (int q = 0; q < 4; ++q) tm[m][q] = fmaxf(sv[m][0][q], sv[m][1][q]);
        #pragma unroll
        for (int off = 1; off <= 8; off <<= 1)
            #pragma unroll
            for (int m = 0; m < 2; ++m)
                #pragma unroll
                for (int q = 0; q < 4; ++q) tm[m][q] = fmaxf(tm[m][q], __shfl_xor(tm[m][q], off));
        if (r16 == 0) {
            #pragma unroll
            for (int m = 0; m < 2; ++m)
                #pragma unroll
                for (int q = 0; q < 4; ++q) s_pmax[wn][lq + (m << 4) + (kl << 2) + q] = tm[m][q];
        }
        __syncthreads();
        if (tid < 64) {
            const float tmx = fmaxf(s_pmax[0][tid], s_pmax[1][tid]);
            const float mo = s_mn[tid];
            const float mn = fmaxf(mo, tmx);
            s_rr[tid] = __expf(mo - mn);
            s_mn[tid] = mn;
        }
        __syncthreads();
        float ps[2][4] = {{0.f, 0.f, 0.f, 0.f}, {0.f, 0.f, 0.f, 0.f}};
        #pragma unroll
        for (int m = 0; m < 2; ++m) {
            #pragma unroll
            for (int q = 0; q < 4; ++q) {
                const int l = lq + (m << 4) + (kl << 2) + q;
                const float mn = s_mn[l];
                #pragma unroll
                for (int nf = 0; nf < 2; ++nf) {
                    const float p = __expf(sv[m][nf][q] - mn);
                    ps[m][q] += p;
                    sP[l][nq + (nf << 4) + r16] = f2bf(p);
                }
            }
        }
        #pragma unroll
        for (int off = 1; off <= 8; off <<= 1)
            #pragma unroll
            for (int m = 0; m < 2; ++m)
                #pragma unroll
                for (int q = 0; q < 4; ++q) ps[m][q] += __shfl_xor(ps[m][q], off);
        if (r16 == 0) {
            #pragma unroll
            for (int m = 0; m < 2; ++m)
                #pragma unroll
                for (int q = 0; q < 4; ++q) s_psum[wn][lq + (m << 4) + (kl << 2) + q] = ps[m][q];
        }
        // rescale PV accumulator (rows = all 64 l per wave)
        #pragma unroll
        for (int m = 0; m < 4; ++m) {
            #pragma unroll
            for (int q = 0; q < 4; ++q) {
                const float rrr = s_rr[(m << 4) + (kl << 2) + q];
                #pragma unroll
                for (int ef = 0; ef < 4; ++ef) acc[m][ef][q] *= rrr;
            }
        }
        __syncthreads();
        if (tid < 64) s_sum[tid] = s_sum[tid] * s_rr[tid] + s_psum[0][tid] + s_psum[1][tid];

        // ---- phase 2: PV, per-wave 64-e slice (no cross-wave barriers) ----
        #pragma unroll
        for (int kk = 0; kk < 2; ++kk) {
            // stage 32 tokens x 64 e transposed into sT[w]
            #pragma unroll
            for (int i = 0; i < 8; ++i) {
                const int u = lane + (i << 6);
                const int n = u >> 4;                 // token 0..31
                const int e4 = (u & 15) << 2;         // e offset
                const float4 fv = *(const float4*)&tokens[(size_t)((b << 12) + n0 + (kk << 5) + n) * DD + e0w + e4];
                ((unsigned short*)&sT[w][e4][n >> 1])[n & 1] = f2bf(fv.x);
                ((unsigned short*)&sT[w][e4 + 1][n >> 1])[n & 1] = f2bf(fv.y);
                ((unsigned short*)&sT[w][e4 + 2][n >> 1])[n & 1] = f2bf(fv.z);
                ((unsigned short*)&sT[w][e4 + 3][n >> 1])[n & 1] = f2bf(fv.w);
            }
            bf16x8 pa[4];
            #pragma unroll
            for (int m = 0; m < 4; ++m)
                pa[m] = *(const bf16x8*)&sP[(m << 4) + r16][(kk << 5) + (kl << 3)];
            #pragma unroll
            for (int ef = 0; ef < 4; ++ef) {
                const bf16x8 bv = *(const bf16x8*)&sT[w][(ef << 4) + r16][kl << 2];
                #pragma unroll
                for (int m = 0; m < 4; ++m)
                    acc[m][ef] = __builtin_amdgcn_mfma_f32_16x16x32_bf16(pa[m], bv, acc[m][ef], 0, 0, 0);
            }
        }
        __syncthreads();
    }

    // ---- write partials (f16) ----
    #pragma unroll
    for (int m = 0; m < 4; ++m) {
        #pragma unroll
        for (int ef = 0; ef < 4; ++ef) {
            #pragma unroll
            for (int q = 0; q < 4; ++q) {
                const int l = (m << 4) + (kl << 2) + q;
                const int e = e0w + (ef << 4) + r16;
                part[(size_t)((z << 10) + (b << 6) + l) * DD + e] = (_Float16)acc[m][ef][q];
            }
        }
    }
    if (tid < 64) {
        mz[(z << 10) + (b << 6) + tid] = s_mn[tid];
        sz[(z << 10) + (b << 6) + tid] = s_sum[tid];
    }
}

// ---------------- K4: combine chunks with rescale + divide ----------------
__global__ __launch_bounds__(256) void k_combine(const _Float16* __restrict__ part,
                                                 const float* __restrict__ mz, const float* __restrict__ sz,
                                                 float* __restrict__ pacc, float* __restrict__ dmg) {
    const int row = blockIdx.x;   // b*64 + l
    const int t = threadIdx.x;
    float mg = MASKVAL;
    float mv[ZCH];
    #pragma unroll
    for (int zz = 0; zz < ZCH; ++zz) {
        mv[zz] = mz[(zz << 10) + row];
        mg = fmaxf(mg, mv[zz]);
    }
    float den = 0.f;
    float fz[ZCH];
    #pragma unroll
    for (int zz = 0; zz < ZCH; ++zz) {
        fz[zz] = __expf(mv[zz] - mg);
        den += sz[(zz << 10) + row] * fz[zz];
    }
    float a0 = 0.f, a1 = 0.f;
    #pragma unroll 8
    for (int zz = 0; zz < ZCH; ++zz) {
        const size_t base = (size_t)((zz << 10) + row) * DD;
        a0 += (float)part[base + t] * fz[zz];
        a1 += (float)part[base + t + 256] * fz[zz];
    }
    const float inv = 1.f / den;
    pacc[(size_t)row * DD + t] = a0 * inv;
    pacc[(size_t)row * DD + t + 256] = a1 * inv;
    if (t == 0) dmg[row] = mg;
}

// ---------------- K5: proj = pacc @ Wv + bv ----------------
__global__ __launch_bounds__(256) void k_proj(const float* __restrict__ pacc, const float* __restrict__ Wv,
                                              const float* __restrict__ bv, float* __restrict__ proj) {
    const int d0 = blockIdx.x * 64;
    const int r0 = blockIdx.y * 64;
    const int tid = threadIdx.x;
    const int rsub = (tid >> 4) << 2;
    const int dsub = (tid & 15) << 2;
    __shared__ float at[64][68];
    __shared__ float wv[64][68];
    float acc[4][4] = {{0.f, 0.f, 0.f, 0.f}};
    for (int kc = 0; kc < 8; ++kc) {
        const int k0 = kc * 64;
        for (int k = tid; k < 1024; k += 256) {
            const int rr = k >> 4, c4 = (k & 15) << 2;
            *(float4*)&at[rr][c4] = *(const float4*)&pacc[(size_t)(r0 + rr) * DD + k0 + c4];
            *(float4*)&wv[rr][c4] = *(const float4*)&Wv[(size_t)(k0 + rr) * DD + d0 + c4];
        }
        __syncthreads();
        #pragma unroll
        for (int n4 = 0; n4 < 16; ++n4) {
            float4 a4[4];
            #pragma unroll
            for (int i = 0; i < 4; ++i) a4[i] = *(const float4*)&at[rsub + i][n4 << 2];
            const float4 b0 = *(const float4*)&wv[(n4 << 2) + 0][dsub];
            const float4 b1 = *(const float4*)&wv[(n4 << 2) + 1][dsub];
            const float4 b2 = *(const float4*)&wv[(n4 << 2) + 2][dsub];
            const float4 b3 = *(const float4*)&wv[(n4 << 2) + 3][dsub];
            #pragma unroll
            for (int i = 0; i < 4; ++i) {
                const float4 av = a4[i];
                acc[i][0] += av.x * b0.x + av.y * b1.x + av.z * b2.x + av.w * b3.x;
                acc[i][1] += av.x * b0.y + av.y * b1.y + av.z * b2.y + av.w * b3.y;
                acc[i][2] += av.x * b0.z + av.y * b1.z + av.z * b2.z + av.w * b3.z;
                acc[i][3] += av.x * b0.w + av.y * b1.w + av.z * b2.w + av.w * b3.w;
            }
        }
        __syncthreads();
    }
    #pragma unroll
    for (int i = 0; i < 4; ++i) {
        const int d = d0 + dsub;
        float4 v;
        v.x = acc[i][0] + bv[d + 0];
        v.y = acc[i][1] + bv[d + 1];
        v.z = acc[i][2] + bv[d + 2];
        v.w = acc[i][3] + bv[d + 3];
        *(float4*)&proj[(size_t)(r0 + rsub + i) * DD + d] = v;
    }
}

// ---------------- K6: RMSNorm + masks + outputs ----------------
__global__ __launch_bounds__(256) void k_rmsout(const float* __restrict__ proj, const float* __restrict__ norm_w,
                                                const float* __restrict__ dmg, float* __restrict__ out) {
    const int row = blockIdx.x;  // b*64 + l
    const int tid = threadIdx.x;
    __shared__ float red[256];
    const float* pr = proj + (size_t)row * DD;
    const float v0 = pr[tid], v1 = pr[tid + 256];
    red[tid] = v0 * v0 + v1 * v1;
    __syncthreads();
    for (int st = 128; st > 0; st >>= 1) {
        if (tid < st) red[tid] += red[tid + st];
        __syncthreads();
    }
    const float var = red[0] / (float)DD;
    const float r = 1.0f / sqrtf(var + RMS_EPS);
    const int ap = (dmg[row] < -1.0e38f) ? 1 : 0;
    const float msk = ap ? 0.f : 1.f;
    out[(size_t)row * DD + tid]       = v0 * r * norm_w[tid] * msk;
    out[(size_t)row * DD + tid + 256] = v1 * r * norm_w[tid + 256] * msk;
    if (tid == 0) out[(size_t)PSZ + row] = ap ? 1.f : 0.f;
}

extern "C" void kernel_launch(void* const* d_in, const int* in_sizes, int n_in,
                              void* d_out, int out_size, void* d_ws, size_t ws_size,
                              hipStream_t stream) {
    const float* query   = (const float*)d_in[0];
    const float* tokens  = (const float*)d_in[1];
    const int*   pmask   = (const int*)d_in[2];
    const float* latents = (const float*)d_in[3];
    const float* Wq = (const float*)d_in[4];
    const float* bq = (const float*)d_in[5];
    const float* Wk = (const float*)d_in[6];
    const float* bk = (const float*)d_in[7];
    const float* Wv = (const float*)d_in[8];
    const float* bv = (const float*)d_in[9];
    const float* nw = (const float*)d_in[10];

    float* ws = (float*)d_ws;
    float* dmg    = ws;                       // 1024
    float* mzv    = ws + 1024;                // 32768
    float* szv    = ws + 33792;               // 32768
    float* qproj  = ws + 66560;               // 8192
    float* Lk     = ws + 74752;               // 32768
    float* Qk     = ws + 107520;              // 8192
    float* sbL    = ws + 115712;              // 64
    float* sbQ    = ws + 115776;              // 64 (pad to 115968)
    unsigned short* LQbf = (unsigned short*)(ws + 115968);   // 524288 ushorts = 262144 floats
    _Float16* part = (_Float16*)(ws + 115968 + 262144);      // 16777216 halves = 8388608 floats
    float* pacc   = ws + 115968 + 262144 + 8388608;          // 524288
    float* proj   = ws + 115968 + 262144 + 8388608 + 524288; // 524288
    float* out    = (float*)d_out;

    k_qproj<<<dim3(8, 16), 256, 0, stream>>>(query, Wq, bq, qproj);
    k_lkqk<<<dim3(8, 80), 256, 0, stream>>>(latents, qproj, Wk, bk, Lk, Qk, sbL, sbQ);
    k_lqbf<<<dim3(64, 16), 256, 0, stream>>>(Lk, Qk, LQbf);
    k_flash<<<dim3(64, 16), 256, 0, stream>>>(tokens, LQbf, sbL, sbQ, pmask, part, mzv, szv);
    k_combine<<<1024, 256, 0, stream>>>(part, mzv, szv, pacc, dmg);
    k_proj<<<dim3(8, 16), 256, 0, stream>>>(pacc, Wv, bv, proj);
    k_rmsout<<<1024, 256, 0, stream>>>(proj, nw, dmg, out);
}

// Round 10
// 149.901 us; speedup vs baseline: 1.1507x; 1.1507x over previous
//
#include <hip/hip_runtime.h>
#include <hip/hip_bf16.h>
#include <math.h>

#define BB 16
#define NN_ 4096
#define DD 512
#define LL 64
#define SCALE 0.044194173824159216f
#define RMS_EPS 1e-6f
#define MASKVAL -3.0e38f
#define PSZ (BB * LL * DD)   // 524288
#define ZCH 16               // N-chunks (256 tokens each, 4 tiles of 64)

using bf16x8 = __attribute__((ext_vector_type(8))) short;
using f32x4  = __attribute__((ext_vector_type(4))) float;

__device__ __forceinline__ unsigned short f2bf(float x) {
    return __bfloat16_as_ushort(__float2bfloat16(x));
}

// ---------------- K1: qproj = query @ Wq + bq ----------------
__global__ __launch_bounds__(256) void k_qproj(const float* __restrict__ query, const float* __restrict__ Wq,
                                               const float* __restrict__ bq, float* __restrict__ qproj) {
    const int b = blockIdx.y;
    const int dl = threadIdx.x & 63;
    const int d = (blockIdx.x << 6) + dl;
    const int wv = threadIdx.x >> 6;
    __shared__ float q[DD];
    __shared__ float red[4][64];
    for (int e = threadIdx.x; e < DD; e += 256) q[e] = query[b * DD + e];
    __syncthreads();
    float acc = 0.f;
    #pragma unroll 8
    for (int i = 0; i < 128; ++i) {
        const int e = (wv << 7) + i;
        acc += q[e] * Wq[(size_t)e * DD + d];
    }
    red[wv][dl] = acc;
    __syncthreads();
    if (threadIdx.x < 64) {
        const int dd = (blockIdx.x << 6) + threadIdx.x;
        qproj[(size_t)b * DD + dd] = red[0][threadIdx.x] + red[1][threadIdx.x] +
                                     red[2][threadIdx.x] + red[3][threadIdx.x] + bq[dd];
    }
}

// ---------------- K2: Lk/Qk = rows @ Wk^T, sbL/sbQ = rows . bk ----------------
__global__ __launch_bounds__(256) void k_lkqk(const float* __restrict__ latents, const float* __restrict__ qproj,
                                              const float* __restrict__ Wk, const float* __restrict__ bk,
                                              float* __restrict__ Lk, float* __restrict__ Qk,
                                              float* __restrict__ sbL, float* __restrict__ sbQ) {
    const int r = blockIdx.y;
    const int e0 = blockIdx.x << 6;
    const int tid = threadIdx.x;
    __shared__ float row[DD];
    const float* src = (r < LL) ? (latents + (size_t)r * DD) : (qproj + (size_t)(r - LL) * DD);
    for (int dd = tid; dd < DD; dd += 256) row[dd] = src[dd];
    __syncthreads();
    const int e = e0 + (tid >> 2);
    const int part = tid & 3;
    const float4* w4 = (const float4*)(Wk + (size_t)e * DD);
    const float4* r4 = (const float4*)row;
    float acc = 0.f;
    #pragma unroll 8
    for (int j = 0; j < 32; ++j) {
        const int d4 = part + (j << 2);
        const float4 w = w4[d4], rr = r4[d4];
        acc += w.x * rr.x + w.y * rr.y + w.z * rr.z + w.w * rr.w;
    }
    acc += __shfl_xor(acc, 1);
    acc += __shfl_xor(acc, 2);
    if (part == 0) {
        if (r < LL) Lk[(size_t)r * DD + e] = acc;
        else        Qk[(size_t)(r - LL) * DD + e] = acc;
    }
    if (blockIdx.x == 0 && tid < 64) {
        float p = 0.f;
        #pragma unroll
        for (int dd = tid; dd < DD; dd += 64) p += bk[dd] * row[dd];
        #pragma unroll
        for (int off = 32; off > 0; off >>= 1) p += __shfl_xor(p, off);
        if (tid == 0) { if (r < LL) sbL[r] = p; else sbQ[r - LL] = p; }
    }
}

// ---------------- K2b: LQbf[b][l][d] = bf16(Lk[l][d] + Qk[b][d]) ----------------
__global__ __launch_bounds__(256) void k_lqbf(const float* __restrict__ Lk, const float* __restrict__ Qk,
                                              unsigned short* __restrict__ LQbf) {
    const int l = blockIdx.x, b = blockIdx.y;
    const int d = threadIdx.x << 1;
    const float2 lv = *(const float2*)&Lk[(size_t)l * DD + d];
    const float2 qv = *(const float2*)&Qk[(size_t)b * DD + d];
    const unsigned o = (unsigned)f2bf(lv.x + qv.x) | ((unsigned)f2bf(lv.y + qv.y) << 16);
    *(unsigned*)&LQbf[(size_t)((b << 6) + l) * DD + d] = o;
}

// ---------------- K3: fused flash (v7: 16-wave blocks, 1 block/CU, 32-reg acc) ----------------
// grid (z=16, b=16) = 256 blocks = #CUs, 1024 threads (16 waves). chunk = 256 tokens.
// QK^T: wave (w&3)=l-block16, (w>>2)=n-block16. PV: wave owns 32-e slice, acc[4][2].
__global__ __launch_bounds__(1024) void k_flash(const float* __restrict__ tokens,
                                                const unsigned short* __restrict__ LQbf,
                                                const float* __restrict__ sbL, const float* __restrict__ sbQ,
                                                const int* __restrict__ pmask,
                                                _Float16* __restrict__ part,
                                                float* __restrict__ mz, float* __restrict__ sz) {
    const int z = blockIdx.x, b = blockIdx.y;
    const int tid = threadIdx.x;
    const int lane = tid & 63, w = tid >> 6;
    const int r16 = lane & 15, kl = lane >> 4;

    __shared__ int sB[2][64][36];         // QK^T token slice [n][d-word], padded, double-buffered
    __shared__ unsigned short sP[64][72]; // P bf16 [l][n]
    __shared__ int sTdn[512][36];         // transposed token pairs [e][n-word], XOR swizzled
    __shared__ float s_mn[64], s_sum[64], s_rr[64];
    __shared__ float s_pmax[4][64], s_psum[4][64];

    const int lq = (w & 3) << 4;        // QK^T wave l-block (16)
    const int nq = (w >> 2) << 4;       // QK^T wave n-block (16)

    f32x4 acc[4][2];                    // PV: 64 l x 32 e per wave
    #pragma unroll
    for (int m = 0; m < 4; ++m)
        #pragma unroll
        for (int ef = 0; ef < 2; ++ef)
            acc[m][ef] = (f32x4){0.f, 0.f, 0.f, 0.f};

    if (tid < 64) { s_mn[tid] = MASKVAL; s_sum[tid] = 0.f; }

    const float sq = sbQ[b];
    const unsigned short* lqrow = &LQbf[(size_t)((b << 6) + lq + r16) * DD];
    float sbl[4];
    #pragma unroll
    for (int q = 0; q < 4; ++q) sbl[q] = sbL[lq + (kl << 2) + q];

    const int st_row = tid >> 4;          // token row 0..63
    const int st_c4 = (tid & 15) << 2;    // d offset
    const int e0w = w << 5;               // PV wave e-slice base
    __syncthreads();

    for (int t = 0; t < 4; ++t) {
        const int n0 = (z << 8) + (t << 6);
        f32x4 accS = (f32x4){0.f, 0.f, 0.f, 0.f};

        // ---- phase 1: QK^T over 8 d-slices, double-buffered sB (1 barrier/slice) ----
        float4 pf = *(const float4*)&tokens[(size_t)((b << 12) + n0 + st_row) * DD + st_c4];
        #pragma unroll
        for (int s8 = 0; s8 < 8; ++s8) {
            const int cur = s8 & 1;
            {
                int2 wa;
                wa.x = (int)((unsigned)f2bf(pf.x) | ((unsigned)f2bf(pf.y) << 16));
                wa.y = (int)((unsigned)f2bf(pf.z) | ((unsigned)f2bf(pf.w) << 16));
                *(int2*)&sB[cur][st_row][st_c4 >> 1] = wa;
            }
            if (s8 < 7)
                pf = *(const float4*)&tokens[(size_t)((b << 12) + n0 + st_row) * DD + ((s8 + 1) << 6) + st_c4];
            __syncthreads();
            #pragma unroll
            for (int kk2 = 0; kk2 < 2; ++kk2) {
                const bf16x8 af = *(const bf16x8*)&lqrow[(s8 << 6) + (kk2 << 5) + (kl << 3)];
                const bf16x8 bfr = *(const bf16x8*)&sB[cur][nq + r16][(kk2 << 4) + (kl << 2)];
                accS = __builtin_amdgcn_mfma_f32_16x16x32_bf16(af, bfr, accS, 0, 0, 0);
            }
        }

        // ---- epilogue: bias+scale+mask, in-register stats ----
        const int ncol = nq + r16;
        const int pm = pmask[(size_t)b * NN_ + n0 + ncol];
        float sv4[4], tm4[4];
        #pragma unroll
        for (int q = 0; q < 4; ++q) {
            const float sval = (accS[q] + sbl[q] + sq) * SCALE;
            sv4[q] = pm ? MASKVAL : sval;
            tm4[q] = sv4[q];
        }
        #pragma unroll
        for (int off = 1; off <= 8; off <<= 1)
            #pragma unroll
            for (int q = 0; q < 4; ++q) tm4[q] = fmaxf(tm4[q], __shfl_xor(tm4[q], off));
        if (r16 == 0) {
            #pragma unroll
            for (int q = 0; q < 4; ++q) s_pmax[w >> 2][lq + (kl << 2) + q] = tm4[q];
        }
        __syncthreads();
        if (tid < 64) {
            const float tmx = fmaxf(fmaxf(s_pmax[0][tid], s_pmax[1][tid]),
                                    fmaxf(s_pmax[2][tid], s_pmax[3][tid]));
            const float mo = s_mn[tid];
            const float mn = fmaxf(mo, tmx);
            s_rr[tid] = __expf(mo - mn);
            s_mn[tid] = mn;
        }
        __syncthreads();
        float ps4[4];
        #pragma unroll
        for (int q = 0; q < 4; ++q) {
            const int l = lq + (kl << 2) + q;
            const float p = __expf(sv4[q] - s_mn[l]);
            ps4[q] = p;
            sP[l][ncol] = f2bf(p);
        }
        #pragma unroll
        for (int off = 1; off <= 8; off <<= 1)
            #pragma unroll
            for (int q = 0; q < 4; ++q) ps4[q] += __shfl_xor(ps4[q], off);
        if (r16 == 0) {
            #pragma unroll
            for (int q = 0; q < 4; ++q) s_psum[w >> 2][lq + (kl << 2) + q] = ps4[q];
        }
        #pragma unroll
        for (int m = 0; m < 4; ++m) {
            #pragma unroll
            for (int q = 0; q < 4; ++q) {
                const float rrr = s_rr[(m << 4) + (kl << 2) + q];
                #pragma unroll
                for (int ef = 0; ef < 2; ++ef) acc[m][ef][q] *= rrr;
            }
        }
        __syncthreads();
        if (tid < 64) s_sum[tid] = s_sum[tid] * s_rr[tid] +
                                   s_psum[0][tid] + s_psum[1][tid] + s_psum[2][tid] + s_psum[3][tid];

        // ---- sTdn staging: transposed token pairs (int-word writes, XOR swizzle) ----
        {
            const int n2 = tid & 31;            // token pair
            const int e16 = (tid >> 5) << 4;    // e window
            const float* tA = &tokens[(size_t)((b << 12) + n0 + (n2 << 1)) * DD + e16];
            #pragma unroll
            for (int h = 0; h < 2; ++h) {
                const float4 a0 = *(const float4*)(tA + (h << 3));
                const float4 a1 = *(const float4*)(tA + (h << 3) + 4);
                const float4 c0 = *(const float4*)(tA + DD + (h << 3));
                const float4 c1 = *(const float4*)(tA + DD + (h << 3) + 4);
                const float* ap0 = (const float*)&a0;
                const float* cp0 = (const float*)&c0;
                const float* ap1 = (const float*)&a1;
                const float* cp1 = (const float*)&c1;
                #pragma unroll
                for (int j = 0; j < 4; ++j) {
                    const int row0 = e16 + (h << 3) + j;
                    const int row1 = row0 + 4;
                    sTdn[row0][n2 ^ (((row0 >> 2) & 7) << 2)] =
                        (int)((unsigned)f2bf(ap0[j]) | ((unsigned)f2bf(cp0[j]) << 16));
                    sTdn[row1][n2 ^ (((row1 >> 2) & 7) << 2)] =
                        (int)((unsigned)f2bf(ap1[j]) | ((unsigned)f2bf(cp1[j]) << 16));
                }
            }
        }
        __syncthreads();

        // ---- phase 2: PV (wave 32-e slice) ----
        #pragma unroll
        for (int kk = 0; kk < 2; ++kk) {
            bf16x8 pa[4];
            #pragma unroll
            for (int m = 0; m < 4; ++m)
                pa[m] = *(const bf16x8*)&sP[(m << 4) + r16][(kk << 5) + (kl << 3)];
            #pragma unroll
            for (int ef = 0; ef < 2; ++ef) {
                const int e = e0w + (ef << 4) + r16;
                const int phys = ((kk << 4) + (kl << 2)) ^ (((e >> 2) & 7) << 2);
                const bf16x8 bv = *(const bf16x8*)&sTdn[e][phys];
                #pragma unroll
                for (int m = 0; m < 4; ++m)
                    acc[m][ef] = __builtin_amdgcn_mfma_f32_16x16x32_bf16(pa[m], bv, acc[m][ef], 0, 0, 0);
            }
        }
        __syncthreads();
    }

    // ---- write partials (f16) ----
    #pragma unroll
    for (int m = 0; m < 4; ++m) {
        #pragma unroll
        for (int ef = 0; ef < 2; ++ef) {
            #pragma unroll
            for (int q = 0; q < 4; ++q) {
                const int l = (m << 4) + (kl << 2) + q;
                const int e = e0w + (ef << 4) + r16;
                part[(size_t)((z << 10) + (b << 6) + l) * DD + e] = (_Float16)acc[m][ef][q];
            }
        }
    }
    if (tid < 64) {
        mz[(z << 10) + (b << 6) + tid] = s_mn[tid];
        sz[(z << 10) + (b << 6) + tid] = s_sum[tid];
    }
}

// ---------------- K4: combine chunks with rescale + divide ----------------
__global__ __launch_bounds__(256) void k_combine(const _Float16* __restrict__ part,
                                                 const float* __restrict__ mz, const float* __restrict__ sz,
                                                 float* __restrict__ pacc, float* __restrict__ dmg) {
    const int row = blockIdx.x;   // b*64 + l
    const int t = threadIdx.x;
    float mg = MASKVAL;
    float mv[ZCH];
    #pragma unroll
    for (int zz = 0; zz < ZCH; ++zz) {
        mv[zz] = mz[(zz << 10) + row];
        mg = fmaxf(mg, mv[zz]);
    }
    float den = 0.f;
    float fz[ZCH];
    #pragma unroll
    for (int zz = 0; zz < ZCH; ++zz) {
        fz[zz] = __expf(mv[zz] - mg);
        den += sz[(zz << 10) + row] * fz[zz];
    }
    float a0 = 0.f, a1 = 0.f;
    #pragma unroll 8
    for (int zz = 0; zz < ZCH; ++zz) {
        const size_t base = (size_t)((zz << 10) + row) * DD;
        a0 += (float)part[base + t] * fz[zz];
        a1 += (float)part[base + t + 256] * fz[zz];
    }
    const float inv = 1.f / den;
    pacc[(size_t)row * DD + t] = a0 * inv;
    pacc[(size_t)row * DD + t + 256] = a1 * inv;
    if (t == 0) dmg[row] = mg;
}

// ---------------- K5: proj = pacc @ Wv + bv ----------------
__global__ __launch_bounds__(256) void k_proj(const float* __restrict__ pacc, const float* __restrict__ Wv,
                                              const float* __restrict__ bv, float* __restrict__ proj) {
    const int d0 = blockIdx.x * 64;
    const int r0 = blockIdx.y * 64;
    const int tid = threadIdx.x;
    const int rsub = (tid >> 4) << 2;
    const int dsub = (tid & 15) << 2;
    __shared__ float at[64][68];
    __shared__ float wv[64][68];
    float acc[4][4] = {{0.f, 0.f, 0.f, 0.f}};
    for (int kc = 0; kc < 8; ++kc) {
        const int k0 = kc * 64;
        for (int k = tid; k < 1024; k += 256) {
            const int rr = k >> 4, c4 = (k & 15) << 2;
            *(float4*)&at[rr][c4] = *(const float4*)&pacc[(size_t)(r0 + rr) * DD + k0 + c4];
            *(float4*)&wv[rr][c4] = *(const float4*)&Wv[(size_t)(k0 + rr) * DD + d0 + c4];
        }
        __syncthreads();
        #pragma unroll
        for (int n4 = 0; n4 < 16; ++n4) {
            float4 a4[4];
            #pragma unroll
            for (int i = 0; i < 4; ++i) a4[i] = *(const float4*)&at[rsub + i][n4 << 2];
            const float4 b0 = *(const float4*)&wv[(n4 << 2) + 0][dsub];
            const float4 b1 = *(const float4*)&wv[(n4 << 2) + 1][dsub];
            const float4 b2 = *(const float4*)&wv[(n4 << 2) + 2][dsub];
            const float4 b3 = *(const float4*)&wv[(n4 << 2) + 3][dsub];
            #pragma unroll
            for (int i = 0; i < 4; ++i) {
                const float4 av = a4[i];
                acc[i][0] += av.x * b0.x + av.y * b1.x + av.z * b2.x + av.w * b3.x;
                acc[i][1] += av.x * b0.y + av.y * b1.y + av.z * b2.y + av.w * b3.y;
                acc[i][2] += av.x * b0.z + av.y * b1.z + av.z * b2.z + av.w * b3.z;
                acc[i][3] += av.x * b0.w + av.y * b1.w + av.z * b2.w + av.w * b3.w;
            }
        }
        __syncthreads();
    }
    #pragma unroll
    for (int i = 0; i < 4; ++i) {
        const int d = d0 + dsub;
        float4 v;
        v.x = acc[i][0] + bv[d + 0];
        v.y = acc[i][1] + bv[d + 1];
        v.z = acc[i][2] + bv[d + 2];
        v.w = acc[i][3] + bv[d + 3];
        *(float4*)&proj[(size_t)(r0 + rsub + i) * DD + d] = v;
    }
}

// ---------------- K6: RMSNorm + masks + outputs ----------------
__global__ __launch_bounds__(256) void k_rmsout(const float* __restrict__ proj, const float* __restrict__ norm_w,
                                                const float* __restrict__ dmg, float* __restrict__ out) {
    const int row = blockIdx.x;  // b*64 + l
    const int tid = threadIdx.x;
    __shared__ float red[256];
    const float* pr = proj + (size_t)row * DD;
    const float v0 = pr[tid], v1 = pr[tid + 256];
    red[tid] = v0 * v0 + v1 * v1;
    __syncthreads();
    for (int st = 128; st > 0; st >>= 1) {
        if (tid < st) red[tid] += red[tid + st];
        __syncthreads();
    }
    const float var = red[0] / (float)DD;
    const float r = 1.0f / sqrtf(var + RMS_EPS);
    const int ap = (dmg[row] < -1.0e38f) ? 1 : 0;
    const float msk = ap ? 0.f : 1.f;
    out[(size_t)row * DD + tid]       = v0 * r * norm_w[tid] * msk;
    out[(size_t)row * DD + tid + 256] = v1 * r * norm_w[tid + 256] * msk;
    if (tid == 0) out[(size_t)PSZ + row] = ap ? 1.f : 0.f;
}

extern "C" void kernel_launch(void* const* d_in, const int* in_sizes, int n_in,
                              void* d_out, int out_size, void* d_ws, size_t ws_size,
                              hipStream_t stream) {
    const float* query   = (const float*)d_in[0];
    const float* tokens  = (const float*)d_in[1];
    const int*   pmask   = (const int*)d_in[2];
    const float* latents = (const float*)d_in[3];
    const float* Wq = (const float*)d_in[4];
    const float* bq = (const float*)d_in[5];
    const float* Wk = (const float*)d_in[6];
    const float* bk = (const float*)d_in[7];
    const float* Wv = (const float*)d_in[8];
    const float* bv = (const float*)d_in[9];
    const float* nw = (const float*)d_in[10];

    float* ws = (float*)d_ws;
    float* dmg    = ws;                       // 1024
    float* mzv    = ws + 1024;                // 16384 (ZCH*1024)
    float* szv    = ws + 17408;               // 16384
    float* qproj  = ws + 33792;               // 8192
    float* Lk     = ws + 41984;               // 32768
    float* Qk     = ws + 74752;               // 8192
    float* sbL    = ws + 82944;               // 64
    float* sbQ    = ws + 83008;               // 64 (pad to 83200)
    unsigned short* LQbf = (unsigned short*)(ws + 83200);    // 524288 ushorts = 262144 floats
    _Float16* part = (_Float16*)(ws + 83200 + 262144);       // ZCH*1024*512 f16 = 4194304 floats
    float* pacc   = ws + 83200 + 262144 + 4194304;           // 524288
    float* proj   = ws + 83200 + 262144 + 4194304 + 524288;  // 524288
    float* out    = (float*)d_out;

    k_qproj<<<dim3(8, 16), 256, 0, stream>>>(query, Wq, bq, qproj);
    k_lkqk<<<dim3(8, 80), 256, 0, stream>>>(latents, qproj, Wk, bk, Lk, Qk, sbL, sbQ);
    k_lqbf<<<dim3(64, 16), 256, 0, stream>>>(Lk, Qk, LQbf);
    k_flash<<<dim3(ZCH, 16), 1024, 0, stream>>>(tokens, LQbf, sbL, sbQ, pmask, part, mzv, szv);
    k_combine<<<1024, 256, 0, stream>>>(part, mzv, szv, pacc, dmg);
    k_proj<<<dim3(8, 16), 256, 0, stream>>>(pacc, Wv, bv, proj);
    k_rmsout<<<1024, 256, 0, stream>>>(proj, nw, dmg, out);
}

// Round 11
// 114.992 us; speedup vs baseline: 1.5000x; 1.3036x over previous
//
#include <hip/hip_runtime.h>
#include <hip/hip_bf16.h>
#include <math.h>

#define BB 16
#define NN_ 4096
#define DD 512
#define LL 64
#define SCALE 0.044194173824159216f
#define RMS_EPS 1e-6f
#define MASKVAL -3.0e38f
#define PSZ (BB * LL * DD)   // 524288
#define ZCH 32               // N-chunks (128 tokens each, 2 tiles of 64)

using bf16x8 = __attribute__((ext_vector_type(8))) short;
using f32x4  = __attribute__((ext_vector_type(4))) float;

__device__ __forceinline__ unsigned short f2bf(float x) {
    return __bfloat16_as_ushort(__float2bfloat16(x));
}

// ---------------- K1: qproj = query @ Wq + bq ----------------
__global__ __launch_bounds__(256) void k_qproj(const float* __restrict__ query, const float* __restrict__ Wq,
                                               const float* __restrict__ bq, float* __restrict__ qproj) {
    const int b = blockIdx.y;
    const int dl = threadIdx.x & 63;
    const int d = (blockIdx.x << 6) + dl;
    const int wv = threadIdx.x >> 6;
    __shared__ float q[DD];
    __shared__ float red[4][64];
    for (int e = threadIdx.x; e < DD; e += 256) q[e] = query[b * DD + e];
    __syncthreads();
    float acc = 0.f;
    #pragma unroll 8
    for (int i = 0; i < 128; ++i) {
        const int e = (wv << 7) + i;
        acc += q[e] * Wq[(size_t)e * DD + d];
    }
    red[wv][dl] = acc;
    __syncthreads();
    if (threadIdx.x < 64) {
        const int dd = (blockIdx.x << 6) + threadIdx.x;
        qproj[(size_t)b * DD + dd] = red[0][threadIdx.x] + red[1][threadIdx.x] +
                                     red[2][threadIdx.x] + red[3][threadIdx.x] + bq[dd];
    }
}

// ---------------- K2: Lk/Qk = rows @ Wk^T, sbL/sbQ = rows . bk ----------------
__global__ __launch_bounds__(256) void k_lkqk(const float* __restrict__ latents, const float* __restrict__ qproj,
                                              const float* __restrict__ Wk, const float* __restrict__ bk,
                                              float* __restrict__ Lk, float* __restrict__ Qk,
                                              float* __restrict__ sbL, float* __restrict__ sbQ) {
    const int r = blockIdx.y;
    const int e0 = blockIdx.x << 6;
    const int tid = threadIdx.x;
    __shared__ float row[DD];
    const float* src = (r < LL) ? (latents + (size_t)r * DD) : (qproj + (size_t)(r - LL) * DD);
    for (int dd = tid; dd < DD; dd += 256) row[dd] = src[dd];
    __syncthreads();
    const int e = e0 + (tid >> 2);
    const int part = tid & 3;
    const float4* w4 = (const float4*)(Wk + (size_t)e * DD);
    const float4* r4 = (const float4*)row;
    float acc = 0.f;
    #pragma unroll 8
    for (int j = 0; j < 32; ++j) {
        const int d4 = part + (j << 2);
        const float4 w = w4[d4], rr = r4[d4];
        acc += w.x * rr.x + w.y * rr.y + w.z * rr.z + w.w * rr.w;
    }
    acc += __shfl_xor(acc, 1);
    acc += __shfl_xor(acc, 2);
    if (part == 0) {
        if (r < LL) Lk[(size_t)r * DD + e] = acc;
        else        Qk[(size_t)(r - LL) * DD + e] = acc;
    }
    if (blockIdx.x == 0 && tid < 64) {
        float p = 0.f;
        #pragma unroll
        for (int dd = tid; dd < DD; dd += 64) p += bk[dd] * row[dd];
        #pragma unroll
        for (int off = 32; off > 0; off >>= 1) p += __shfl_xor(p, off);
        if (tid == 0) { if (r < LL) sbL[r] = p; else sbQ[r - LL] = p; }
    }
}

// ---------------- K2b: LQbf[b][l][d] = bf16(Lk[l][d] + Qk[b][d]) ----------------
__global__ __launch_bounds__(256) void k_lqbf(const float* __restrict__ Lk, const float* __restrict__ Qk,
                                              unsigned short* __restrict__ LQbf) {
    const int l = blockIdx.x, b = blockIdx.y;
    const int d = threadIdx.x << 1;
    const float2 lv = *(const float2*)&Lk[(size_t)l * DD + d];
    const float2 qv = *(const float2*)&Qk[(size_t)b * DD + d];
    const unsigned o = (unsigned)f2bf(lv.x + qv.x) | ((unsigned)f2bf(lv.y + qv.y) << 16);
    *(unsigned*)&LQbf[(size_t)((b << 6) + l) * DD + d] = o;
}

// ---------------- K3: fused flash (v8: 8 waves, (512,2), per-wave PV tiles, 2 blocks/CU) ----------------
// grid (z=32, b=16) = 512 blocks, 512 threads. chunk = 128 tokens = 2 tiles of 64.
__global__ __launch_bounds__(512, 2) void k_flash(const float* __restrict__ tokens,
                                                  const unsigned short* __restrict__ LQbf,
                                                  const float* __restrict__ sbL, const float* __restrict__ sbQ,
                                                  const int* __restrict__ pmask,
                                                  _Float16* __restrict__ part,
                                                  float* __restrict__ mz, float* __restrict__ sz) {
    const int z = blockIdx.x, b = blockIdx.y;
    const int tid = threadIdx.x;
    const int lane = tid & 63, w = tid >> 6;
    const int r16 = lane & 15, kl = lane >> 4;

    __shared__ int sB[2][64][36];         // QK^T token slice [n][d-word], dbuf
    __shared__ unsigned short sP[64][72]; // P bf16 [l][n(64)]
    __shared__ int sTw[8][64][20];        // per-wave PV window [e(64)][pair(16)+pad], XOR swizzled
    __shared__ float s_mn[64], s_sum[64], s_rr[64];
    __shared__ float s_pmax[2][64], s_psum[2][64];

    const int lq = (w & 3) << 4;        // QK^T wave l-block (16)
    const int nq = (w >> 2) << 5;       // QK^T wave n-block (32, two 16-tiles)

    f32x4 acc[4][4];                    // PV: 64 l x 64 e per wave
    #pragma unroll
    for (int m = 0; m < 4; ++m)
        #pragma unroll
        for (int ef = 0; ef < 4; ++ef)
            acc[m][ef] = (f32x4){0.f, 0.f, 0.f, 0.f};

    if (tid < 64) { s_mn[tid] = MASKVAL; s_sum[tid] = 0.f; }

    const float sq = sbQ[b];
    const unsigned short* lqrow = &LQbf[(size_t)((b << 6) + lq + r16) * DD];
    float sbl[4];
    #pragma unroll
    for (int q = 0; q < 4; ++q) sbl[q] = sbL[lq + (kl << 2) + q];

    // phase-1 staging: pair = tid>>4 (0..31), dblk = tid&15
    const int p1_pair = tid >> 4;
    const int p1_d4 = (tid & 15) << 2;
    const int e0w = w << 6;               // PV wave e-slice base (64)
    __syncthreads();

    for (int t = 0; t < 2; ++t) {
        const int n0 = (z << 7) + (t << 6);
        f32x4 accS[2];
        accS[0] = (f32x4){0.f, 0.f, 0.f, 0.f};
        accS[1] = (f32x4){0.f, 0.f, 0.f, 0.f};

        // ---- phase 1: QK^T over 8 d-slices, dbuf sB, 1 barrier/slice ----
        const float* tbase = &tokens[(size_t)((b << 12) + n0 + (p1_pair << 1)) * DD + p1_d4];
        float4 pf0 = *(const float4*)tbase;
        float4 pf1 = *(const float4*)(tbase + DD);
        #pragma unroll
        for (int s8 = 0; s8 < 8; ++s8) {
            const int cur = s8 & 1;
            {
                int2 w0, w1;
                w0.x = (int)((unsigned)f2bf(pf0.x) | ((unsigned)f2bf(pf0.y) << 16));
                w0.y = (int)((unsigned)f2bf(pf0.z) | ((unsigned)f2bf(pf0.w) << 16));
                w1.x = (int)((unsigned)f2bf(pf1.x) | ((unsigned)f2bf(pf1.y) << 16));
                w1.y = (int)((unsigned)f2bf(pf1.z) | ((unsigned)f2bf(pf1.w) << 16));
                *(int2*)&sB[cur][(p1_pair << 1)][p1_d4 >> 1] = w0;
                *(int2*)&sB[cur][(p1_pair << 1) + 1][p1_d4 >> 1] = w1;
            }
            if (s8 < 7) {
                pf0 = *(const float4*)(tbase + ((s8 + 1) << 6));
                pf1 = *(const float4*)(tbase + DD + ((s8 + 1) << 6));
            }
            __syncthreads();
            #pragma unroll
            for (int kk2 = 0; kk2 < 2; ++kk2) {
                const bf16x8 af = *(const bf16x8*)&lqrow[(s8 << 6) + (kk2 << 5) + (kl << 3)];
                #pragma unroll
                for (int nf = 0; nf < 2; ++nf) {
                    const bf16x8 bfr = *(const bf16x8*)&sB[cur][nq + (nf << 4) + r16][(kk2 << 4) + (kl << 2)];
                    accS[nf] = __builtin_amdgcn_mfma_f32_16x16x32_bf16(af, bfr, accS[nf], 0, 0, 0);
                }
            }
        }

        // ---- epilogue: bias+scale+mask, in-register stats ----
        float sv[2][4], tm4[4];
        #pragma unroll
        for (int nf = 0; nf < 2; ++nf) {
            const int ncol = nq + (nf << 4) + r16;
            const int pm = pmask[(size_t)(b << 12) + n0 + ncol];
            #pragma unroll
            for (int q = 0; q < 4; ++q) {
                const float sval = (accS[nf][q] + sbl[q] + sq) * SCALE;
                sv[nf][q] = pm ? MASKVAL : sval;
            }
        }
        #pragma unroll
        for (int q = 0; q < 4; ++q) tm4[q] = fmaxf(sv[0][q], sv[1][q]);
        #pragma unroll
        for (int off = 1; off <= 8; off <<= 1)
            #pragma unroll
            for (int q = 0; q < 4; ++q) tm4[q] = fmaxf(tm4[q], __shfl_xor(tm4[q], off));
        if (r16 == 0) {
            #pragma unroll
            for (int q = 0; q < 4; ++q) s_pmax[w >> 2][lq + (kl << 2) + q] = tm4[q];
        }
        __syncthreads();
        if (tid < 64) {
            const float tmx = fmaxf(s_pmax[0][tid], s_pmax[1][tid]);
            const float mo = s_mn[tid];
            const float mn = fmaxf(mo, tmx);
            s_rr[tid] = __expf(mo - mn);
            s_mn[tid] = mn;
        }
        __syncthreads();
        float ps4[4];
        #pragma unroll
        for (int q = 0; q < 4; ++q) {
            const int l = lq + (kl << 2) + q;
            const float mn = s_mn[l];
            const float p0 = __expf(sv[0][q] - mn);
            const float p1 = __expf(sv[1][q] - mn);
            sP[l][nq + r16] = f2bf(p0);
            sP[l][nq + 16 + r16] = f2bf(p1);
            ps4[q] = p0 + p1;
        }
        #pragma unroll
        for (int off = 1; off <= 8; off <<= 1)
            #pragma unroll
            for (int q = 0; q < 4; ++q) ps4[q] += __shfl_xor(ps4[q], off);
        if (r16 == 0) {
            #pragma unroll
            for (int q = 0; q < 4; ++q) s_psum[w >> 2][lq + (kl << 2) + q] = ps4[q];
        }
        // rescale PV accumulator (all 64 l rows per wave)
        #pragma unroll
        for (int m = 0; m < 4; ++m) {
            #pragma unroll
            for (int q = 0; q < 4; ++q) {
                const float rrr = s_rr[(m << 4) + (kl << 2) + q];
                #pragma unroll
                for (int ef = 0; ef < 4; ++ef) acc[m][ef][q] *= rrr;
            }
        }
        __syncthreads();
        if (tid < 64) s_sum[tid] = s_sum[tid] * s_rr[tid] + s_psum[0][tid] + s_psum[1][tid];

        // ---- phase 2: PV, per-wave 64-e slice, two 32-token windows, no cross-wave barriers ----
        #pragma unroll
        for (int kk = 0; kk < 2; ++kk) {
            // stage window: 32 tokens (16 pairs) x 64 e, int-pair writes, XOR swizzle
            #pragma unroll
            for (int rep = 0; rep < 4; ++rep) {
                const int p = (lane >> 4) + (rep << 2);       // pair 0..15
                const int e4 = (lane & 15) << 2;              // e offset
                const float* tp = &tokens[(size_t)((b << 12) + n0 + (kk << 5) + (p << 1)) * DD + e0w + e4];
                const float4 t0 = *(const float4*)tp;
                const float4 t1 = *(const float4*)(tp + DD);
                const float* a0 = (const float*)&t0;
                const float* a1 = (const float*)&t1;
                #pragma unroll
                for (int j = 0; j < 4; ++j) {
                    const int e = e4 + j;
                    const int col = p ^ (((((e >> 2) ^ (e >> 4))) & 3) << 2);
                    sTw[w][e][col] = (int)((unsigned)f2bf(a0[j]) | ((unsigned)f2bf(a1[j]) << 16));
                }
            }
            bf16x8 pa[4];
            #pragma unroll
            for (int m = 0; m < 4; ++m)
                pa[m] = *(const bf16x8*)&sP[(m << 4) + r16][(kk << 5) + (kl << 3)];
            #pragma unroll
            for (int ef = 0; ef < 4; ++ef) {
                const int e = (ef << 4) + r16;
                const int col4 = (kl << 2) ^ (((((e >> 2) ^ (e >> 4))) & 3) << 2);
                const bf16x8 bv = *(const bf16x8*)&sTw[w][e][col4];
                #pragma unroll
                for (int m = 0; m < 4; ++m)
                    acc[m][ef] = __builtin_amdgcn_mfma_f32_16x16x32_bf16(pa[m], bv, acc[m][ef], 0, 0, 0);
            }
        }
        __syncthreads();
    }

    // ---- write partials (f16) ----
    #pragma unroll
    for (int m = 0; m < 4; ++m) {
        #pragma unroll
        for (int ef = 0; ef < 4; ++ef) {
            #pragma unroll
            for (int q = 0; q < 4; ++q) {
                const int l = (m << 4) + (kl << 2) + q;
                const int e = e0w + (ef << 4) + r16;
                part[(size_t)((z << 10) + (b << 6) + l) * DD + e] = (_Float16)acc[m][ef][q];
            }
        }
    }
    if (tid < 64) {
        mz[(z << 10) + (b << 6) + tid] = s_mn[tid];
        sz[(z << 10) + (b << 6) + tid] = s_sum[tid];
    }
}

// ---------------- K4: combine chunks with rescale + divide ----------------
__global__ __launch_bounds__(256) void k_combine(const _Float16* __restrict__ part,
                                                 const float* __restrict__ mz, const float* __restrict__ sz,
                                                 float* __restrict__ pacc, float* __restrict__ dmg) {
    const int row = blockIdx.x;   // b*64 + l
    const int t = threadIdx.x;
    float mg = MASKVAL;
    float mv[ZCH];
    #pragma unroll
    for (int zz = 0; zz < ZCH; ++zz) {
        mv[zz] = mz[(zz << 10) + row];
        mg = fmaxf(mg, mv[zz]);
    }
    float den = 0.f;
    float fz[ZCH];
    #pragma unroll
    for (int zz = 0; zz < ZCH; ++zz) {
        fz[zz] = __expf(mv[zz] - mg);
        den += sz[(zz << 10) + row] * fz[zz];
    }
    float a0 = 0.f, a1 = 0.f;
    #pragma unroll 8
    for (int zz = 0; zz < ZCH; ++zz) {
        const size_t base = (size_t)((zz << 10) + row) * DD;
        a0 += (float)part[base + t] * fz[zz];
        a1 += (float)part[base + t + 256] * fz[zz];
    }
    const float inv = 1.f / den;
    pacc[(size_t)row * DD + t] = a0 * inv;
    pacc[(size_t)row * DD + t + 256] = a1 * inv;
    if (t == 0) dmg[row] = mg;
}

// ---------------- K5: proj = pacc @ Wv + bv ----------------
__global__ __launch_bounds__(256) void k_proj(const float* __restrict__ pacc, const float* __restrict__ Wv,
                                              const float* __restrict__ bv, float* __restrict__ proj) {
    const int d0 = blockIdx.x * 64;
    const int r0 = blockIdx.y * 64;
    const int tid = threadIdx.x;
    const int rsub = (tid >> 4) << 2;
    const int dsub = (tid & 15) << 2;
    __shared__ float at[64][68];
    __shared__ float wv[64][68];
    float acc[4][4] = {{0.f, 0.f, 0.f, 0.f}};
    for (int kc = 0; kc < 8; ++kc) {
        const int k0 = kc * 64;
        for (int k = tid; k < 1024; k += 256) {
            const int rr = k >> 4, c4 = (k & 15) << 2;
            *(float4*)&at[rr][c4] = *(const float4*)&pacc[(size_t)(r0 + rr) * DD + k0 + c4];
            *(float4*)&wv[rr][c4] = *(const float4*)&Wv[(size_t)(k0 + rr) * DD + d0 + c4];
        }
        __syncthreads();
        #pragma unroll
        for (int n4 = 0; n4 < 16; ++n4) {
            float4 a4[4];
            #pragma unroll
            for (int i = 0; i < 4; ++i) a4[i] = *(const float4*)&at[rsub + i][n4 << 2];
            const float4 b0 = *(const float4*)&wv[(n4 << 2) + 0][dsub];
            const float4 b1 = *(const float4*)&wv[(n4 << 2) + 1][dsub];
            const float4 b2 = *(const float4*)&wv[(n4 << 2) + 2][dsub];
            const float4 b3 = *(const float4*)&wv[(n4 << 2) + 3][dsub];
            #pragma unroll
            for (int i = 0; i < 4; ++i) {
                const float4 av = a4[i];
                acc[i][0] += av.x * b0.x + av.y * b1.x + av.z * b2.x + av.w * b3.x;
                acc[i][1] += av.x * b0.y + av.y * b1.y + av.z * b2.y + av.w * b3.y;
                acc[i][2] += av.x * b0.z + av.y * b1.z + av.z * b2.z + av.w * b3.z;
                acc[i][3] += av.x * b0.w + av.y * b1.w + av.z * b2.w + av.w * b3.w;
            }
        }
        __syncthreads();
    }
    #pragma unroll
    for (int i = 0; i < 4; ++i) {
        const int d = d0 + dsub;
        float4 v;
        v.x = acc[i][0] + bv[d + 0];
        v.y = acc[i][1] + bv[d + 1];
        v.z = acc[i][2] + bv[d + 2];
        v.w = acc[i][3] + bv[d + 3];
        *(float4*)&proj[(size_t)(r0 + rsub + i) * DD + d] = v;
    }
}

// ---------------- K6: RMSNorm + masks + outputs ----------------
__global__ __launch_bounds__(256) void k_rmsout(const float* __restrict__ proj, const float* __restrict__ norm_w,
                                                const float* __restrict__ dmg, float* __restrict__ out) {
    const int row = blockIdx.x;  // b*64 + l
    const int tid = threadIdx.x;
    __shared__ float red[256];
    const float* pr = proj + (size_t)row * DD;
    const float v0 = pr[tid], v1 = pr[tid + 256];
    red[tid] = v0 * v0 + v1 * v1;
    __syncthreads();
    for (int st = 128; st > 0; st >>= 1) {
        if (tid < st) red[tid] += red[tid + st];
        __syncthreads();
    }
    const float var = red[0] / (float)DD;
    const float r = 1.0f / sqrtf(var + RMS_EPS);
    const int ap = (dmg[row] < -1.0e38f) ? 1 : 0;
    const float msk = ap ? 0.f : 1.f;
    out[(size_t)row * DD + tid]       = v0 * r * norm_w[tid] * msk;
    out[(size_t)row * DD + tid + 256] = v1 * r * norm_w[tid + 256] * msk;
    if (tid == 0) out[(size_t)PSZ + row] = ap ? 1.f : 0.f;
}

extern "C" void kernel_launch(void* const* d_in, const int* in_sizes, int n_in,
                              void* d_out, int out_size, void* d_ws, size_t ws_size,
                              hipStream_t stream) {
    const float* query   = (const float*)d_in[0];
    const float* tokens  = (const float*)d_in[1];
    const int*   pmask   = (const int*)d_in[2];
    const float* latents = (const float*)d_in[3];
    const float* Wq = (const float*)d_in[4];
    const float* bq = (const float*)d_in[5];
    const float* Wk = (const float*)d_in[6];
    const float* bk = (const float*)d_in[7];
    const float* Wv = (const float*)d_in[8];
    const float* bv = (const float*)d_in[9];
    const float* nw = (const float*)d_in[10];

    float* ws = (float*)d_ws;
    float* dmg    = ws;                       // 1024
    float* mzv    = ws + 1024;                // 32768
    float* szv    = ws + 33792;               // 32768
    float* qproj  = ws + 66560;               // 8192
    float* Lk     = ws + 74752;               // 32768
    float* Qk     = ws + 107520;              // 8192
    float* sbL    = ws + 115712;              // 64
    float* sbQ    = ws + 115776;              // 64 (pad to 115968)
    unsigned short* LQbf = (unsigned short*)(ws + 115968);   // 524288 ushorts = 262144 floats
    _Float16* part = (_Float16*)(ws + 115968 + 262144);      // 16777216 halves = 8388608 floats
    float* pacc   = ws + 115968 + 262144 + 8388608;          // 524288
    float* proj   = ws + 115968 + 262144 + 8388608 + 524288; // 524288
    float* out    = (float*)d_out;

    k_qproj<<<dim3(8, 16), 256, 0, stream>>>(query, Wq, bq, qproj);
    k_lkqk<<<dim3(8, 80), 256, 0, stream>>>(latents, qproj, Wk, bk, Lk, Qk, sbL, sbQ);
    k_lqbf<<<dim3(64, 16), 256, 0, stream>>>(Lk, Qk, LQbf);
    k_flash<<<dim3(ZCH, 16), 512, 0, stream>>>(tokens, LQbf, sbL, sbQ, pmask, part, mzv, szv);
    k_combine<<<1024, 256, 0, stream>>>(part, mzv, szv, pacc, dmg);
    k_proj<<<dim3(8, 16), 256, 0, stream>>>(pacc, Wv, bv, proj);
    k_rmsout<<<1024, 256, 0, stream>>>(proj, nw, dmg, out);
}